// Round 9
// baseline (1274.073 us; speedup 1.0000x reference)
//
#include <hip/hip_runtime.h>

typedef __attribute__((ext_vector_type(8))) short short8;
typedef __attribute__((ext_vector_type(4))) float f32x4;

#define DEV __device__ __forceinline__

DEV unsigned short f2bf(float f) {
  union { float f; unsigned u; } x; x.f = f;
  unsigned r = x.u + 0x7FFFu + ((x.u >> 16) & 1u);
  return (unsigned short)(r >> 16);
}
DEV float bf2f(short h) {
  union { unsigned u; float f; } x; x.u = ((unsigned)(unsigned short)h) << 16;
  return x.f;
}

// async global->LDS, 16B per lane; LDS dest is wave-uniform base + lane*16
DEV void gload16(const void* g, void* l) {
  __builtin_amdgcn_global_load_lds(
      (const __attribute__((address_space(1))) unsigned int*)g,
      (__attribute__((address_space(3))) unsigned int*)l, 16, 0, 0);
}

#define BARRIER() do { asm volatile("" ::: "memory"); \
  __builtin_amdgcn_s_barrier(); asm volatile("" ::: "memory"); } while (0)
#define WAIT_LGKM0() asm volatile("s_waitcnt lgkmcnt(0)" ::: "memory")
#define WAIT_VM8() asm volatile("s_waitcnt vmcnt(8)" ::: "memory")
#define WAIT_VM0() asm volatile("s_waitcnt vmcnt(0)" ::: "memory")
// per-wave counted wait: w<8 waves issue 4 gloads/tile, w>=8 issue 3
#define WAIT_VM_TILE() do { if (w < 8) { \
    asm volatile("s_waitcnt vmcnt(4)" ::: "memory"); \
  } else { \
    asm volatile("s_waitcnt vmcnt(3)" ::: "memory"); } } while (0)

// ---------------- weight conversion (head-major reorder for qkv) ----------------
// qkv weights: source row r = h*64+d  ->  dest row h*192 + sel*64 + d  (sel=q0,k1,v2)
struct CvtW { const float* s[7]; short* d[7]; };
__global__ __launch_bounds__(256) void cvt_weights(CvtW a) {
  int i = (blockIdx.x * 256 + threadIdx.x) * 8;   // 1024*1024 elems
  int r = i >> 10, cix = i & 1023;
  int hh = r >> 6, dd = r & 63;
  #pragma unroll
  for (int m = 0; m < 7; ++m) {
    const float* s = a.s[m] + i;
    float4 v0 = *(const float4*)(s);
    float4 v1 = *(const float4*)(s + 4);
    short8 o;
    o[0] = (short)f2bf(v0.x); o[1] = (short)f2bf(v0.y);
    o[2] = (short)f2bf(v0.z); o[3] = (short)f2bf(v0.w);
    o[4] = (short)f2bf(v1.x); o[5] = (short)f2bf(v1.y);
    o[6] = (short)f2bf(v1.z); o[7] = (short)f2bf(v1.w);
    int dr = (m < 6) ? (hh * 192 + (m % 3) * 64 + dd) : r;
    *(short8*)(a.d[m] + (size_t)dr * 1024 + cix) = o;
  }
}

struct CvtB { const float* s[6]; float* d0; float* d1; };
__global__ __launch_bounds__(256) void cvt_bias(CvtB a) {
  int m = blockIdx.x;
  const float* s = a.s[m];
  float* dst = (m < 3) ? a.d0 : a.d1;
  int j = threadIdx.x * 4;                 // 4 consecutive, same head
  int hh = j >> 6, dd = j & 63;
  float4 v = *(const float4*)(s + j);
  *(float4*)(dst + hh * 192 + (m % 3) * 64 + dd) = v;
}

// ---------------- x -> x_ant (gather + fp32->bf16), 16B stores ----------------
__global__ __launch_bounds__(256) void permute_x(const float* __restrict__ x,
                                                 short* __restrict__ xa) {
  int m = blockIdx.x * 2 + (threadIdx.x >> 7);   // 32768 blocks -> 65536 rows
  int a = m & 31, n = m >> 5;
  int g = n & 3, b = n >> 2;
  int c = (threadIdx.x & 127) * 8;
  size_t src = ((size_t)b * 129 + 1 + (size_t)a * 4 + g) * 1024 + c;
  float4 v0 = *(const float4*)(x + src);
  float4 v1 = *(const float4*)(x + src + 4);
  short8 o;
  o[0] = (short)f2bf(v0.x); o[1] = (short)f2bf(v0.y);
  o[2] = (short)f2bf(v0.z); o[3] = (short)f2bf(v0.w);
  o[4] = (short)f2bf(v1.x); o[5] = (short)f2bf(v1.y);
  o[6] = (short)f2bf(v1.z); o[7] = (short)f2bf(v1.w);
  *(short8*)(xa + (size_t)m * 1024 + c) = o;
}

// =================== fused GEMM(256x192) + per-head attention ===================
// 1024 thr / 16 waves (4M x 4N, wave tile 64x48), BK=64, 2x buffered LDS,
// stage-ahead-2 (tile kt stages kt+2 into the SAME buffer c=kt&1).
// Pipelined single-phase K-tile: all B + A(q0,q1) ds_reads issued upfront,
// A(q2)/A(q3) issued between MFMA groups; compiler emits counted lgkmcnt.
// 2 barriers per K-tile. Counted per-wave vmcnt (T4). XOR-swizzled LDS.
#define MFMA_GRP(q, AF) do { \
  __builtin_amdgcn_s_setprio(1); \
  _Pragma("unroll") for (int kk = 0; kk < 2; ++kk) \
    _Pragma("unroll") for (int nf = 0; nf < 3; ++nf) \
      acc[q][nf] = __builtin_amdgcn_mfma_f32_16x16x32_bf16( \
          AF[kk], bf3[nf][kk], acc[q][nf], 0, 0, 0); \
  __builtin_amdgcn_s_setprio(0); } while (0)

#define LOAD_A16(DST, q) do { \
  const char* pa = base + wm * 8192 + ((q)*16 + l15) * 128; \
  DST[0] = *(const short8*)(pa + swz0); \
  DST[1] = *(const short8*)(pa + swz1); \
} while (0)

template <int STAGE>   // 1: ant attn (S=32) epilogue; 2: freq attn (S=4) epilogue
__global__ __launch_bounds__(1024)
void gemm_attn(const short* __restrict__ A, const short* __restrict__ Bm,
               const float* __restrict__ bias, short* __restrict__ Outp, int K) {
  extern __shared__ char ls[];
  int nwg = gridDim.x;
  int bid = blockIdx.x;
  bid = (bid & 7) * (nwg >> 3) + (bid >> 3);   // XCD swizzle (grid %8==0)
  int tm = (bid >> 4) << 8;                    // M tile
  int hh = bid & 15;                           // head
  int t = threadIdx.x;
  int lane = t & 63, w = t >> 6;               // 16 waves
  int wm = w >> 2, wn = w & 3;                 // 4M x 4N
  int l15 = lane & 15, l4 = lane >> 4;
  int cg = (lane & 7) ^ ((lane >> 3) & 7);

  // staging sources: A units w, w+16 (8 rows each); B units w (+ w+16 if w<8)
  const short* aS[2];
  #pragma unroll
  for (int s = 0; s < 2; ++s) {
    int r = (w + s * 16) * 8 + (lane >> 3);
    aS[s] = A + (size_t)(tm + r) * K + cg * 8;
  }
  const short* bS0 = Bm + (size_t)(hh * 192 + w * 8 + (lane >> 3)) * K + cg * 8;
  const short* bS1 = Bm + (size_t)(hh * 192 + ((w & 7) + 16) * 8 + (lane >> 3)) * K + cg * 8;

  auto stageA = [&](int c, int kt) {
    gload16(aS[0] + kt * 64, ls + c * 65536 + w * 1024);
    gload16(aS[1] + kt * 64, ls + c * 65536 + (w + 16) * 1024);
  };
  auto stageB = [&](int c, int kt) {
    gload16(bS0 + kt * 64, ls + c * 65536 + 32768 + w * 1024);
    if (w < 8) gload16(bS1 + kt * 64, ls + c * 65536 + 32768 + (16 + w) * 1024);
  };
  int swz0 = ((l4 ^ (l15 & 7)) << 4);
  int swz1 = swz0 ^ 64;

  f32x4 acc[4][3];
  #pragma unroll
  for (int m = 0; m < 4; ++m)
    #pragma unroll
    for (int n = 0; n < 3; ++n) acc[m][n] = (f32x4){0.f, 0.f, 0.f, 0.f};

  int NT = K >> 6;
  // prologue: stage K-tiles 0,1
  stageB(0, 0); stageA(0, 0);
  stageB(1, 1); stageA(1, 1);
  WAIT_VM_TILE();              // tile-0 loads (this wave's) landed
  BARRIER();

  for (int kt = 0; kt < NT; ++kt) {
    int c = kt & 1;
    const char* base = ls + c * 65536;
    bool stg = (kt + 2) < NT;
    short8 bf3[3][2], afA[2], afB[2], afC[2], afD[2];
    // issue all B-frag reads + A q0,q1
    #pragma unroll
    for (int nf = 0; nf < 3; ++nf) {
      const char* p = base + 32768 + (wn * 48 + nf * 16 + l15) * 128;
      bf3[nf][0] = *(const short8*)(p + swz0);
      bf3[nf][1] = *(const short8*)(p + swz1);
    }
    LOAD_A16(afA, 0);
    LOAD_A16(afB, 1);
    // MFMA q0 while A q2 reads issue
    MFMA_GRP(0, afA);
    LOAD_A16(afC, 2);
    MFMA_GRP(1, afB);
    LOAD_A16(afD, 3);
    MFMA_GRP(2, afC);
    MFMA_GRP(3, afD);
    WAIT_LGKM0();              // all own reads of buffer c done
    BARRIER();                 // block-wide: buffer c free for restage
    if (stg) { stageA(c, kt + 2); stageB(c, kt + 2); }
    if (stg) { WAIT_VM_TILE(); } else { WAIT_VM0(); }   // tile kt+1 resident
    BARRIER();
  }

  // ---- write qkv tile (bias added) to LDS, pitch 200 bf16 (400 B) ----
  const float* bb = bias + hh * 192;
  #pragma unroll
  for (int nf = 0; nf < 3; ++nf) {
    int col = wn * 48 + nf * 16 + l15;
    float bv = bb[col];
    #pragma unroll
    for (int mf = 0; mf < 4; ++mf)
      #pragma unroll
      for (int j = 0; j < 4; ++j) {
        int row = wm * 64 + mf * 16 + l4 * 4 + j;
        *(short*)(ls + row * 400 + col * 2) = (short)f2bf(acc[mf][nf][j] + bv);
      }
  }
  WAIT_LGKM0();
  BARRIER();

  if constexpr (STAGE == 1) {
    if (w < 8) {
      // per-wave attention, n-group = w (rows w*32..w*32+31), S=32, DK=64
      const char* qk = ls + (size_t)(w * 32) * 400;
      short8 qf[2][2], kf[2][2];
      #pragma unroll
      for (int mt = 0; mt < 2; ++mt)
        #pragma unroll
        for (int kk = 0; kk < 2; ++kk) {
          int row = mt * 16 + l15;
          qf[mt][kk] = *(const short8*)(qk + row * 400 + (kk * 32 + l4 * 8) * 2);
          kf[mt][kk] = *(const short8*)(qk + row * 400 + 128 + (kk * 32 + l4 * 8) * 2);
        }
      f32x4 sf[2][2];
      #pragma unroll
      for (int mt = 0; mt < 2; ++mt)
        #pragma unroll
        for (int nt = 0; nt < 2; ++nt) sf[mt][nt] = (f32x4){0.f, 0.f, 0.f, 0.f};
      #pragma unroll
      for (int kk = 0; kk < 2; ++kk)
        #pragma unroll
        for (int mt = 0; mt < 2; ++mt)
          #pragma unroll
          for (int nt = 0; nt < 2; ++nt)
            sf[mt][nt] = __builtin_amdgcn_mfma_f32_16x16x32_bf16(qf[mt][kk], kf[nt][kk], sf[mt][nt], 0, 0, 0);

      short* Pw = (short*)(ls + 102400 + w * 2560);   // [32][40] per wave
      #pragma unroll
      for (int mt = 0; mt < 2; ++mt)
        #pragma unroll
        for (int j = 0; j < 4; ++j) {
          float a0 = sf[mt][0][j] * 0.125f;
          float a1 = sf[mt][1][j] * 0.125f;
          float mx = fmaxf(a0, a1);
          mx = fmaxf(mx, __shfl_xor(mx, 1));
          mx = fmaxf(mx, __shfl_xor(mx, 2));
          mx = fmaxf(mx, __shfl_xor(mx, 4));
          mx = fmaxf(mx, __shfl_xor(mx, 8));
          float e0 = __expf(a0 - mx), e1 = __expf(a1 - mx);
          float sm = e0 + e1;
          sm += __shfl_xor(sm, 1);
          sm += __shfl_xor(sm, 2);
          sm += __shfl_xor(sm, 4);
          sm += __shfl_xor(sm, 8);
          float inv = 1.0f / sm;
          int row = mt * 16 + l4 * 4 + j;
          Pw[row * 40 + l15]      = (short)f2bf(e0 * inv);
          Pw[row * 40 + 16 + l15] = (short)f2bf(e1 * inv);
        }
      WAIT_LGKM0();

      short8 pa[2], vb[4];
      pa[0] = *(const short8*)(Pw + l15 * 40 + l4 * 8);
      pa[1] = *(const short8*)(Pw + (16 + l15) * 40 + l4 * 8);
      #pragma unroll
      for (int nt = 0; nt < 4; ++nt) {
        short8 v;
        #pragma unroll
        for (int j = 0; j < 8; ++j)
          v[j] = *(const short*)(qk + (l4 * 8 + j) * 400 + 256 + (nt * 16 + l15) * 2);
        vb[nt] = v;
      }
      f32x4 of[2][4];
      #pragma unroll
      for (int mt = 0; mt < 2; ++mt)
        #pragma unroll
        for (int nt = 0; nt < 4; ++nt) of[mt][nt] = (f32x4){0.f, 0.f, 0.f, 0.f};
      #pragma unroll
      for (int mt = 0; mt < 2; ++mt)
        #pragma unroll
        for (int nt = 0; nt < 4; ++nt)
          of[mt][nt] = __builtin_amdgcn_mfma_f32_16x16x32_bf16(pa[mt], vb[nt], of[mt][nt], 0, 0, 0);

      int nn = (tm >> 5) + w;
      int b = nn >> 2, g = nn & 3;
      #pragma unroll
      for (int mt = 0; mt < 2; ++mt)
        #pragma unroll
        for (int j = 0; j < 4; ++j) {
          int q = mt * 16 + l4 * 4 + j;
          size_t orow = (((size_t)b * 32 + q) * 4 + g) * 1024 + hh * 64;
          #pragma unroll
          for (int nt = 0; nt < 4; ++nt)
            Outp[orow + nt * 16 + l15] = (short)f2bf(of[mt][nt][j]);
        }
    }
  } else {
    // S=4 attention: 64 groups of 4 rows; 8 threads/group (gq, d-half)
    if (t < 512) {
      int gi = t >> 3, s = t & 7, gq = s >> 1, dh = s & 1;
      const char* grp = ls + (size_t)(gi * 4) * 400;
      short8 q8[4];
      #pragma unroll
      for (int c = 0; c < 4; ++c)
        q8[c] = *(const short8*)(grp + gq * 400 + dh * 64 + c * 16);
      float dot[4];
      #pragma unroll
      for (int k = 0; k < 4; ++k) {
        float p = 0.f;
        #pragma unroll
        for (int c = 0; c < 4; ++c) {
          short8 k8 = *(const short8*)(grp + k * 400 + 128 + dh * 64 + c * 16);
          #pragma unroll
          for (int j = 0; j < 8; ++j) p += bf2f(q8[c][j]) * bf2f(k8[j]);
        }
        p += __shfl_xor(p, 1);
        dot[k] = p * 0.125f;
      }
      float mx = fmaxf(fmaxf(dot[0], dot[1]), fmaxf(dot[2], dot[3]));
      float e[4], sm = 0.f;
      #pragma unroll
      for (int k = 0; k < 4; ++k) { e[k] = __expf(dot[k] - mx); sm += e[k]; }
      float inv = 1.0f / sm;
      float o[32];
      #pragma unroll
      for (int j = 0; j < 32; ++j) o[j] = 0.f;
      #pragma unroll
      for (int k = 0; k < 4; ++k) {
        float pk = e[k] * inv;
        #pragma unroll
        for (int c = 0; c < 4; ++c) {
          short8 v8 = *(const short8*)(grp + k * 400 + 256 + dh * 64 + c * 16);
          #pragma unroll
          for (int j = 0; j < 8; ++j) o[c * 8 + j] += pk * bf2f(v8[j]);
        }
      }
      int n4 = ((tm >> 2) + gi) * 4 + gq;
      short* orow = Outp + (size_t)n4 * 1024 + hh * 64 + dh * 32;
      #pragma unroll
      for (int c = 0; c < 4; ++c) {
        short8 a8;
        #pragma unroll
        for (int j = 0; j < 8; ++j) a8[j] = (short)f2bf(o[c * 8 + j]);
        *(short8*)(orow + c * 8) = a8;
      }
    }
  }
}

// =================== final projection GEMM (256x256) + mean/cls fusion =========
#define PH_MFMA(q) do { \
  __builtin_amdgcn_s_setprio(1); \
  _Pragma("unroll") for (int kk = 0; kk < 2; ++kk) \
    _Pragma("unroll") for (int m = 0; m < 2; ++m) \
      _Pragma("unroll") for (int nf = 0; nf < 4; ++nf) \
        acc[(q)*2+m][nf] = __builtin_amdgcn_mfma_f32_16x16x32_bf16( \
            af[m][kk], bf[nf][kk], acc[(q)*2+m][nf], 0, 0, 0); \
  __builtin_amdgcn_s_setprio(0); } while (0)

#define LOAD_A(q) do { \
  const char* pa = base + aRdBase + ((q)*32 + l15) * 128; \
  af[0][0] = *(const short8*)(pa + swz0); \
  af[0][1] = *(const short8*)(pa + swz1); \
  af[1][0] = *(const short8*)(pa + 2048 + swz0); \
  af[1][1] = *(const short8*)(pa + 2048 + swz1); \
} while (0)

__global__ __launch_bounds__(512, 2)
void gemm_out(const short* __restrict__ A, const short* __restrict__ Bm,
              const float* __restrict__ bias, const float* __restrict__ x,
              float* __restrict__ Out, int M, int N, int K) {
  extern __shared__ char ls[];
  int nbn = N >> 8;
  int nwg = gridDim.x;
  int bid = blockIdx.x;
  bid = (bid & 7) * (nwg >> 3) + (bid >> 3);
  int tm = (bid / nbn) << 8;
  int tn = (bid % nbn) << 8;
  int t = threadIdx.x;
  int lane = t & 63, w = t >> 6;
  int wm = w >> 2, wn = w & 3;
  int l15 = lane & 15, l4 = lane >> 4;
  int cg = (lane & 7) ^ ((lane >> 3) & 7);
  const short* aS[2][2];
  const short* bS[2][2];
  #pragma unroll
  for (int h = 0; h < 2; ++h)
    #pragma unroll
    for (int i = 0; i < 2; ++i) {
      int r = h * 128 + (w * 2 + i) * 8 + (lane >> 3);
      aS[h][i] = A + (size_t)(tm + r) * K + cg * 8;
      bS[h][i] = Bm + (size_t)(tn + r) * K + cg * 8;
    }
  int dstOff = (w * 2) * 1024;
  auto stageA = [&](int c, int kt) {
    #pragma unroll
    for (int h = 0; h < 2; ++h)
      #pragma unroll
      for (int i = 0; i < 2; ++i)
        gload16(aS[h][i] + kt * 64, ls + c * 65536 + h * 16384 + dstOff + i * 1024);
  };
  auto stageB = [&](int c, int kt, int h) {
    #pragma unroll
    for (int i = 0; i < 2; ++i)
      gload16(bS[h][i] + kt * 64, ls + c * 65536 + 32768 + h * 16384 + dstOff + i * 1024);
  };
  int aRdBase = wm * 16384;
  int bRdBase = 32768 + (wn >> 1) * 16384;
  int bRow0 = (wn & 1) * 64;
  int swz0 = ((l4 ^ (l15 & 7)) << 4);
  int swz1 = swz0 ^ 64;
  f32x4 acc[8][4];
  #pragma unroll
  for (int m = 0; m < 8; ++m)
    #pragma unroll
    for (int n = 0; n < 4; ++n) acc[m][n] = (f32x4){0.f, 0.f, 0.f, 0.f};
  int NT = K >> 6;
  stageB(0, 0, 0); stageB(0, 0, 1); stageA(0, 0);
  stageB(1, 1, 0); stageB(1, 1, 1); stageA(1, 1);
  WAIT_VM8();
  BARRIER();
  for (int kt = 0; kt < NT; ++kt) {
    int c = kt & 1;
    const char* base = ls + c * 65536;
    bool stg = (kt + 2) < NT;
    short8 bf[4][2], af[2][2];
    #pragma unroll
    for (int nf = 0; nf < 4; ++nf) {
      const char* p = base + bRdBase + (bRow0 + nf * 16 + l15) * 128;
      bf[nf][0] = *(const short8*)(p + swz0);
      bf[nf][1] = *(const short8*)(p + swz1);
    }
    LOAD_A(0);
    BARRIER();
    PH_MFMA(0);
    BARRIER();
    if (stg) stageB(c, kt + 2, 0);
    LOAD_A(1);
    BARRIER();
    PH_MFMA(1);
    BARRIER();
    if (stg) stageB(c, kt + 2, 1);
    LOAD_A(2);
    BARRIER();
    PH_MFMA(2);
    BARRIER();
    LOAD_A(3);
    WAIT_LGKM0();
    BARRIER();
    if (stg) stageA(c, kt + 2);
    PH_MFMA(3);
    if (stg) { WAIT_VM8(); } else { WAIT_VM0(); }
    BARRIER();
  }
  int b = (tm >> 7) + wm;
  #pragma unroll
  for (int nf = 0; nf < 4; ++nf) {
    int colg = tn + wn * 64 + nf * 16 + l15;
    float bv = bias[colg];
    float s = 0.f;
    #pragma unroll
    for (int mf = 0; mf < 8; ++mf)
      #pragma unroll
      for (int j = 0; j < 4; ++j) s += acc[mf][nf][j];
    s += 32.0f * bv;
    s += __shfl_xor(s, 16);
    s += __shfl_xor(s, 32);
    float cls = x[(size_t)b * 129 * 1024 + colg] + s * (1.0f / 128.0f);
    if (l4 == 0)
      Out[((size_t)b * 129) * 1024 + colg] = cls;
    #pragma unroll
    for (int mf = 0; mf < 8; ++mf) {
      #pragma unroll
      for (int j = 0; j < 4; ++j) {
        int tok = mf * 16 + l4 * 4 + j;
        Out[((size_t)b * 129 + 1 + tok) * 1024 + colg] = acc[mf][nf][j] + bv + cls;
      }
    }
  }
}

// ---------------- host ----------------
extern "C" void kernel_launch(void* const* d_in, const int* in_sizes, int n_in,
                              void* d_out, int out_size, void* d_ws, size_t ws_size,
                              hipStream_t stream) {
  const float* x        = (const float*)d_in[0];
  const float* w_q_ant  = (const float*)d_in[1];
  const float* b_q_ant  = (const float*)d_in[2];
  const float* w_k_ant  = (const float*)d_in[3];
  const float* b_k_ant  = (const float*)d_in[4];
  const float* w_v_ant  = (const float*)d_in[5];
  const float* b_v_ant  = (const float*)d_in[6];
  const float* w_q_freq = (const float*)d_in[7];
  const float* b_q_freq = (const float*)d_in[8];
  const float* w_k_freq = (const float*)d_in[9];
  const float* b_k_freq = (const float*)d_in[10];
  const float* w_v_freq = (const float*)d_in[11];
  const float* b_v_freq = (const float*)d_in[12];
  const float* w_out    = (const float*)d_in[13];
  const float* b_out    = (const float*)d_in[14];

  char* ws = (char*)d_ws;
  size_t off = 0;
  auto carve = [&](size_t bytes) {
    char* p = ws + off;
    off += (bytes + 255) & ~(size_t)255;
    return p;
  };
  short* wcat_ant  = (short*)carve((size_t)3072 * 1024 * 2);
  short* wcat_freq = (short*)carve((size_t)3072 * 1024 * 2);
  short* wout_bf   = (short*)carve((size_t)1024 * 1024 * 2);
  float* bcat_ant  = (float*)carve(3072 * 4);
  float* bcat_freq = (float*)carve(3072 * 4);
  short* bufA = (short*)carve((size_t)65536 * 1024 * 2);  // x_ant
  short* bufF = (short*)carve((size_t)65536 * 1024 * 2);  // x_freq
  short* bufG = (short*)carve((size_t)65536 * 1024 * 2);  // grid_flat
  (void)ws_size; (void)in_sizes; (void)n_in; (void)out_size;

  hipFuncSetAttribute((const void*)gemm_attn<1>,
                      hipFuncAttributeMaxDynamicSharedMemorySize, 131072);
  hipFuncSetAttribute((const void*)gemm_attn<2>,
                      hipFuncAttributeMaxDynamicSharedMemorySize, 131072);
  hipFuncSetAttribute((const void*)gemm_out,
                      hipFuncAttributeMaxDynamicSharedMemorySize, 131072);

  CvtW cw;
  cw.s[0] = w_q_ant;  cw.s[1] = w_k_ant;  cw.s[2] = w_v_ant;
  cw.s[3] = w_q_freq; cw.s[4] = w_k_freq; cw.s[5] = w_v_freq;
  cw.s[6] = w_out;
  cw.d[0] = wcat_ant;  cw.d[1] = wcat_ant;  cw.d[2] = wcat_ant;
  cw.d[3] = wcat_freq; cw.d[4] = wcat_freq; cw.d[5] = wcat_freq;
  cw.d[6] = wout_bf;
  cvt_weights<<<512, 256, 0, stream>>>(cw);

  CvtB cb;
  cb.s[0] = b_q_ant;  cb.s[1] = b_k_ant;  cb.s[2] = b_v_ant;
  cb.s[3] = b_q_freq; cb.s[4] = b_k_freq; cb.s[5] = b_v_freq;
  cb.d0 = bcat_ant; cb.d1 = bcat_freq;
  cvt_bias<<<6, 256, 0, stream>>>(cb);

  permute_x<<<32768, 256, 0, stream>>>(x, bufA);

  // stage 1: fused qkv GEMM + ant attention -> x_freq
  gemm_attn<1><<<4096, 1024, 131072, stream>>>(bufA, wcat_ant, bcat_ant, bufF, 1024);
  // stage 2: fused qkv GEMM + freq attention -> grid_flat
  gemm_attn<2><<<4096, 1024, 131072, stream>>>(bufF, wcat_freq, bcat_freq, bufG, 1024);
  // out projection fused with mean/cls/concat -> d_out
  gemm_out<<<1024, 512, 131072, stream>>>(bufG, wout_bf, b_out, x, (float*)d_out,
                                          65536, 1024, 1024);
}

// Round 10
// 1204.610 us; speedup vs baseline: 1.0577x; 1.0577x over previous
//
#include <hip/hip_runtime.h>

typedef __attribute__((ext_vector_type(8))) short short8;
typedef __attribute__((ext_vector_type(4))) float f32x4;

#define DEV __device__ __forceinline__

DEV unsigned short f2bf(float f) {
  union { float f; unsigned u; } x; x.f = f;
  unsigned r = x.u + 0x7FFFu + ((x.u >> 16) & 1u);
  return (unsigned short)(r >> 16);
}
DEV float bf2f(short h) {
  union { unsigned u; float f; } x; x.u = ((unsigned)(unsigned short)h) << 16;
  return x.f;
}

// async global->LDS, 16B per lane; LDS dest is wave-uniform base + lane*16
DEV void gload16(const void* g, void* l) {
  __builtin_amdgcn_global_load_lds(
      (const __attribute__((address_space(1))) unsigned int*)g,
      (__attribute__((address_space(3))) unsigned int*)l, 16, 0, 0);
}

#define BARRIER() do { asm volatile("" ::: "memory"); \
  __builtin_amdgcn_s_barrier(); asm volatile("" ::: "memory"); } while (0)
#define WAIT_LGKM0() asm volatile("s_waitcnt lgkmcnt(0)" ::: "memory")
#define WAIT_VM8() asm volatile("s_waitcnt vmcnt(8)" ::: "memory")
#define WAIT_VM7() asm volatile("s_waitcnt vmcnt(7)" ::: "memory")
#define WAIT_VM0() asm volatile("s_waitcnt vmcnt(0)" ::: "memory")

// ---------------- weight conversion (head-major reorder for qkv) ----------------
// qkv weights: source row r = h*64+d  ->  dest row h*192 + sel*64 + d  (sel=q0,k1,v2)
struct CvtW { const float* s[7]; short* d[7]; };
__global__ __launch_bounds__(256) void cvt_weights(CvtW a) {
  int i = (blockIdx.x * 256 + threadIdx.x) * 8;   // 1024*1024 elems
  int r = i >> 10, cix = i & 1023;
  int hh = r >> 6, dd = r & 63;
  #pragma unroll
  for (int m = 0; m < 7; ++m) {
    const float* s = a.s[m] + i;
    float4 v0 = *(const float4*)(s);
    float4 v1 = *(const float4*)(s + 4);
    short8 o;
    o[0] = (short)f2bf(v0.x); o[1] = (short)f2bf(v0.y);
    o[2] = (short)f2bf(v0.z); o[3] = (short)f2bf(v0.w);
    o[4] = (short)f2bf(v1.x); o[5] = (short)f2bf(v1.y);
    o[6] = (short)f2bf(v1.z); o[7] = (short)f2bf(v1.w);
    int dr = (m < 6) ? (hh * 192 + (m % 3) * 64 + dd) : r;
    *(short8*)(a.d[m] + (size_t)dr * 1024 + cix) = o;
  }
}

struct CvtB { const float* s[6]; float* d0; float* d1; };
__global__ __launch_bounds__(256) void cvt_bias(CvtB a) {
  int m = blockIdx.x;
  const float* s = a.s[m];
  float* dst = (m < 3) ? a.d0 : a.d1;
  int j = threadIdx.x * 4;                 // 4 consecutive, same head
  int hh = j >> 6, dd = j & 63;
  float4 v = *(const float4*)(s + j);
  *(float4*)(dst + hh * 192 + (m % 3) * 64 + dd) = v;
}

// ---------------- x -> x_ant (gather + fp32->bf16), 16B stores ----------------
__global__ __launch_bounds__(256) void permute_x(const float* __restrict__ x,
                                                 short* __restrict__ xa) {
  int m = blockIdx.x * 2 + (threadIdx.x >> 7);   // 32768 blocks -> 65536 rows
  int a = m & 31, n = m >> 5;
  int g = n & 3, b = n >> 2;
  int c = (threadIdx.x & 127) * 8;
  size_t src = ((size_t)b * 129 + 1 + (size_t)a * 4 + g) * 1024 + c;
  float4 v0 = *(const float4*)(x + src);
  float4 v1 = *(const float4*)(x + src + 4);
  short8 o;
  o[0] = (short)f2bf(v0.x); o[1] = (short)f2bf(v0.y);
  o[2] = (short)f2bf(v0.z); o[3] = (short)f2bf(v0.w);
  o[4] = (short)f2bf(v1.x); o[5] = (short)f2bf(v1.y);
  o[6] = (short)f2bf(v1.z); o[7] = (short)f2bf(v1.w);
  *(short8*)(xa + (size_t)m * 1024 + c) = o;
}

// =================== fused GEMM(256x192) + per-head attention ===================
// A[M,1024] bf16, Bm = head-major wcat [3072][1024], 512 thr (8 waves 2Mx4N).
// LDS per buffer (stride 64KB): A rows 0..255 @0 (32KB), B rows 0..191 @32768 (24KB).
// XOR swizzle: LDS[row][cc] = global[row][cc ^ (row&7)] (16B chunks).
// Schedule: stage-ahead-2 (tile kt stages kt+2 into the SAME buffer c=kt&1),
// counted vmcnt(7) at tile end — never drain to 0 in the main loop (T4).
#define PH_MFMA3(q) do { \
  __builtin_amdgcn_s_setprio(1); \
  _Pragma("unroll") for (int kk = 0; kk < 2; ++kk) \
    _Pragma("unroll") for (int m = 0; m < 2; ++m) \
      _Pragma("unroll") for (int nf = 0; nf < 3; ++nf) \
        acc[(q)*2+m][nf] = __builtin_amdgcn_mfma_f32_16x16x32_bf16( \
            af[m][kk], bf3[nf][kk], acc[(q)*2+m][nf], 0, 0, 0); \
  __builtin_amdgcn_s_setprio(0); } while (0)

#define LOAD_A(q) do { \
  const char* pa = base + aRdBase + ((q)*32 + l15) * 128; \
  af[0][0] = *(const short8*)(pa + swz0); \
  af[0][1] = *(const short8*)(pa + swz1); \
  af[1][0] = *(const short8*)(pa + 2048 + swz0); \
  af[1][1] = *(const short8*)(pa + 2048 + swz1); \
} while (0)

template <int STAGE>   // 1: ant attn (S=32) epilogue; 2: freq attn (S=4) epilogue
__global__ __launch_bounds__(512, 2)
void gemm_attn(const short* __restrict__ A, const short* __restrict__ Bm,
               const float* __restrict__ bias, short* __restrict__ Outp, int K) {
  extern __shared__ char ls[];
  int nwg = gridDim.x;
  int bid = blockIdx.x;
  bid = (bid & 7) * (nwg >> 3) + (bid >> 3);   // XCD swizzle (grid %8==0)
  int tm = (bid >> 4) << 8;                    // M tile
  int hh = bid & 15;                           // head
  int t = threadIdx.x;
  int lane = t & 63, w = t >> 6;
  int wm = w >> 2, wn = w & 3;
  int l15 = lane & 15, l4 = lane >> 4;
  int cg = (lane & 7) ^ ((lane >> 3) & 7);

  const short* aS[2][2];
  #pragma unroll
  for (int h = 0; h < 2; ++h)
    #pragma unroll
    for (int i = 0; i < 2; ++i) {
      int r = h * 128 + (w * 2 + i) * 8 + (lane >> 3);
      aS[h][i] = A + (size_t)(tm + r) * K + cg * 8;
    }
  const short* bS[3];
  #pragma unroll
  for (int j = 0; j < 3; ++j) {
    int r = j * 64 + w * 8 + (lane >> 3);
    bS[j] = Bm + (size_t)(hh * 192 + r) * K + cg * 8;
  }
  int dstOff = (w * 2) * 1024;
  auto stageA = [&](int c, int kt) {
    #pragma unroll
    for (int h = 0; h < 2; ++h)
      #pragma unroll
      for (int i = 0; i < 2; ++i)
        gload16(aS[h][i] + kt * 64, ls + c * 65536 + h * 16384 + dstOff + i * 1024);
  };
  auto stageB = [&](int c, int kt, int j) {
    gload16(bS[j] + kt * 64, ls + c * 65536 + 32768 + j * 8192 + w * 1024);
  };
  int aRdBase = wm * 16384;
  int swz0 = ((l4 ^ (l15 & 7)) << 4);
  int swz1 = swz0 ^ 64;

  f32x4 acc[8][3];
  #pragma unroll
  for (int m = 0; m < 8; ++m)
    #pragma unroll
    for (int n = 0; n < 3; ++n) acc[m][n] = (f32x4){0.f, 0.f, 0.f, 0.f};

  int NT = K >> 6;
  // prologue: stage K-tiles 0,1
  stageB(0, 0, 0); stageB(0, 0, 1); stageB(0, 0, 2); stageA(0, 0);
  stageB(1, 1, 0); stageB(1, 1, 1); stageB(1, 1, 2); stageA(1, 1);
  WAIT_VM7();
  BARRIER();

  for (int kt = 0; kt < NT; ++kt) {
    int c = kt & 1;
    const char* base = ls + c * 65536;
    bool stg = (kt + 2) < NT;
    short8 bf3[3][2], af[2][2];
    // phase 0: all B frags + A q0
    #pragma unroll
    for (int nf = 0; nf < 3; ++nf) {
      const char* p = base + 32768 + (wn * 48 + nf * 16 + l15) * 128;
      bf3[nf][0] = *(const short8*)(p + swz0);
      bf3[nf][1] = *(const short8*)(p + swz1);
    }
    LOAD_A(0);
    BARRIER();
    PH_MFMA3(0);
    BARRIER();                 // all waves consumed B LDS -> B region free
    // phase 1
    if (stg) { stageB(c, kt + 2, 0); stageB(c, kt + 2, 1); }
    LOAD_A(1);
    BARRIER();
    PH_MFMA3(1);
    BARRIER();
    // phase 2
    if (stg) stageB(c, kt + 2, 2);
    LOAD_A(2);
    BARRIER();
    PH_MFMA3(2);
    BARRIER();
    // phase 3
    LOAD_A(3);
    WAIT_LGKM0();              // own A reads in regs
    BARRIER();                 // all waves done reading A region
    if (stg) stageA(c, kt + 2);
    PH_MFMA3(3);
    if (stg) { WAIT_VM7(); } else { WAIT_VM0(); }   // K-tile kt+1 resident
    BARRIER();
  }

  // ---- write qkv tile (bias added) to LDS, pitch 200 bf16 (400 B) ----
  const float* bb = bias + hh * 192;
  #pragma unroll
  for (int nf = 0; nf < 3; ++nf) {
    int col = wn * 48 + nf * 16 + l15;
    float bv = bb[col];
    #pragma unroll
    for (int mf = 0; mf < 8; ++mf)
      #pragma unroll
      for (int j = 0; j < 4; ++j) {
        int row = wm * 128 + mf * 16 + l4 * 4 + j;
        *(short*)(ls + row * 400 + col * 2) = (short)f2bf(acc[mf][nf][j] + bv);
      }
  }
  WAIT_LGKM0();
  BARRIER();

  if constexpr (STAGE == 1) {
    // per-wave attention, n-group = w (rows w*32..w*32+31), S=32, DK=64
    const char* qk = ls + (size_t)(w * 32) * 400;
    short8 qf[2][2], kf[2][2];
    #pragma unroll
    for (int mt = 0; mt < 2; ++mt)
      #pragma unroll
      for (int kk = 0; kk < 2; ++kk) {
        int row = mt * 16 + l15;
        qf[mt][kk] = *(const short8*)(qk + row * 400 + (kk * 32 + l4 * 8) * 2);
        kf[mt][kk] = *(const short8*)(qk + row * 400 + 128 + (kk * 32 + l4 * 8) * 2);
      }
    f32x4 sf[2][2];
    #pragma unroll
    for (int mt = 0; mt < 2; ++mt)
      #pragma unroll
      for (int nt = 0; nt < 2; ++nt) sf[mt][nt] = (f32x4){0.f, 0.f, 0.f, 0.f};
    #pragma unroll
    for (int kk = 0; kk < 2; ++kk)
      #pragma unroll
      for (int mt = 0; mt < 2; ++mt)
        #pragma unroll
        for (int nt = 0; nt < 2; ++nt)
          sf[mt][nt] = __builtin_amdgcn_mfma_f32_16x16x32_bf16(qf[mt][kk], kf[nt][kk], sf[mt][nt], 0, 0, 0);

    short* Pw = (short*)(ls + 102400 + w * 2560);   // [32][40] per wave
    #pragma unroll
    for (int mt = 0; mt < 2; ++mt)
      #pragma unroll
      for (int j = 0; j < 4; ++j) {
        float a0 = sf[mt][0][j] * 0.125f;
        float a1 = sf[mt][1][j] * 0.125f;
        float mx = fmaxf(a0, a1);
        mx = fmaxf(mx, __shfl_xor(mx, 1));
        mx = fmaxf(mx, __shfl_xor(mx, 2));
        mx = fmaxf(mx, __shfl_xor(mx, 4));
        mx = fmaxf(mx, __shfl_xor(mx, 8));
        float e0 = __expf(a0 - mx), e1 = __expf(a1 - mx);
        float sm = e0 + e1;
        sm += __shfl_xor(sm, 1);
        sm += __shfl_xor(sm, 2);
        sm += __shfl_xor(sm, 4);
        sm += __shfl_xor(sm, 8);
        float inv = 1.0f / sm;
        int row = mt * 16 + l4 * 4 + j;
        Pw[row * 40 + l15]      = (short)f2bf(e0 * inv);
        Pw[row * 40 + 16 + l15] = (short)f2bf(e1 * inv);
      }
    WAIT_LGKM0();

    short8 pa[2], vb[4];
    pa[0] = *(const short8*)(Pw + l15 * 40 + l4 * 8);
    pa[1] = *(const short8*)(Pw + (16 + l15) * 40 + l4 * 8);
    #pragma unroll
    for (int nt = 0; nt < 4; ++nt) {
      short8 v;
      #pragma unroll
      for (int j = 0; j < 8; ++j)
        v[j] = *(const short*)(qk + (l4 * 8 + j) * 400 + 256 + (nt * 16 + l15) * 2);
      vb[nt] = v;
    }
    f32x4 of[2][4];
    #pragma unroll
    for (int mt = 0; mt < 2; ++mt)
      #pragma unroll
      for (int nt = 0; nt < 4; ++nt) of[mt][nt] = (f32x4){0.f, 0.f, 0.f, 0.f};
    #pragma unroll
    for (int mt = 0; mt < 2; ++mt)
      #pragma unroll
      for (int nt = 0; nt < 4; ++nt)
        of[mt][nt] = __builtin_amdgcn_mfma_f32_16x16x32_bf16(pa[mt], vb[nt], of[mt][nt], 0, 0, 0);

    int nn = (tm >> 5) + w;
    int b = nn >> 2, g = nn & 3;
    #pragma unroll
    for (int mt = 0; mt < 2; ++mt)
      #pragma unroll
      for (int j = 0; j < 4; ++j) {
        int q = mt * 16 + l4 * 4 + j;
        size_t orow = (((size_t)b * 32 + q) * 4 + g) * 1024 + hh * 64;
        #pragma unroll
        for (int nt = 0; nt < 4; ++nt)
          Outp[orow + nt * 16 + l15] = (short)f2bf(of[mt][nt][j]);
      }
  } else {
    // S=4 attention: 64 groups of 4 rows; 8 threads/group (gq, d-half)
    int gi = t >> 3, s = t & 7, gq = s >> 1, dh = s & 1;
    const char* grp = ls + (size_t)(gi * 4) * 400;
    short8 q8[4];
    #pragma unroll
    for (int c = 0; c < 4; ++c)
      q8[c] = *(const short8*)(grp + gq * 400 + dh * 64 + c * 16);
    float dot[4];
    #pragma unroll
    for (int k = 0; k < 4; ++k) {
      float p = 0.f;
      #pragma unroll
      for (int c = 0; c < 4; ++c) {
        short8 k8 = *(const short8*)(grp + k * 400 + 128 + dh * 64 + c * 16);
        #pragma unroll
        for (int j = 0; j < 8; ++j) p += bf2f(q8[c][j]) * bf2f(k8[j]);
      }
      p += __shfl_xor(p, 1);
      dot[k] = p * 0.125f;
    }
    float mx = fmaxf(fmaxf(dot[0], dot[1]), fmaxf(dot[2], dot[3]));
    float e[4], sm = 0.f;
    #pragma unroll
    for (int k = 0; k < 4; ++k) { e[k] = __expf(dot[k] - mx); sm += e[k]; }
    float inv = 1.0f / sm;
    float o[32];
    #pragma unroll
    for (int j = 0; j < 32; ++j) o[j] = 0.f;
    #pragma unroll
    for (int k = 0; k < 4; ++k) {
      float pk = e[k] * inv;
      #pragma unroll
      for (int c = 0; c < 4; ++c) {
        short8 v8 = *(const short8*)(grp + k * 400 + 256 + dh * 64 + c * 16);
        #pragma unroll
        for (int j = 0; j < 8; ++j) o[c * 8 + j] += pk * bf2f(v8[j]);
      }
    }
    int n4 = ((tm >> 2) + gi) * 4 + gq;
    short* orow = Outp + (size_t)n4 * 1024 + hh * 64 + dh * 32;
    #pragma unroll
    for (int c = 0; c < 4; ++c) {
      short8 a8;
      #pragma unroll
      for (int j = 0; j < 8; ++j) a8[j] = (short)f2bf(o[c * 8 + j]);
      *(short8*)(orow + c * 8) = a8;
    }
  }
}

// =================== final projection GEMM (256x256) + mean/cls fusion =========
#define PH_MFMA(q) do { \
  __builtin_amdgcn_s_setprio(1); \
  _Pragma("unroll") for (int kk = 0; kk < 2; ++kk) \
    _Pragma("unroll") for (int m = 0; m < 2; ++m) \
      _Pragma("unroll") for (int nf = 0; nf < 4; ++nf) \
        acc[(q)*2+m][nf] = __builtin_amdgcn_mfma_f32_16x16x32_bf16( \
            af[m][kk], bf[nf][kk], acc[(q)*2+m][nf], 0, 0, 0); \
  __builtin_amdgcn_s_setprio(0); } while (0)

__global__ __launch_bounds__(512, 2)
void gemm_out(const short* __restrict__ A, const short* __restrict__ Bm,
              const float* __restrict__ bias, const float* __restrict__ x,
              float* __restrict__ Out, int M, int N, int K) {
  extern __shared__ char ls[];
  int nbn = N >> 8;
  int nwg = gridDim.x;
  int bid = blockIdx.x;
  bid = (bid & 7) * (nwg >> 3) + (bid >> 3);
  int tm = (bid / nbn) << 8;
  int tn = (bid % nbn) << 8;
  int t = threadIdx.x;
  int lane = t & 63, w = t >> 6;
  int wm = w >> 2, wn = w & 3;
  int l15 = lane & 15, l4 = lane >> 4;
  int cg = (lane & 7) ^ ((lane >> 3) & 7);
  const short* aS[2][2];
  const short* bS[2][2];
  #pragma unroll
  for (int h = 0; h < 2; ++h)
    #pragma unroll
    for (int i = 0; i < 2; ++i) {
      int r = h * 128 + (w * 2 + i) * 8 + (lane >> 3);
      aS[h][i] = A + (size_t)(tm + r) * K + cg * 8;
      bS[h][i] = Bm + (size_t)(tn + r) * K + cg * 8;
    }
  int dstOff = (w * 2) * 1024;
  auto stageA = [&](int c, int kt) {
    #pragma unroll
    for (int h = 0; h < 2; ++h)
      #pragma unroll
      for (int i = 0; i < 2; ++i)
        gload16(aS[h][i] + kt * 64, ls + c * 65536 + h * 16384 + dstOff + i * 1024);
  };
  auto stageB = [&](int c, int kt, int h) {
    #pragma unroll
    for (int i = 0; i < 2; ++i)
      gload16(bS[h][i] + kt * 64, ls + c * 65536 + 32768 + h * 16384 + dstOff + i * 1024);
  };
  int aRdBase = wm * 16384;
  int bRdBase = 32768 + (wn >> 1) * 16384;
  int bRow0 = (wn & 1) * 64;
  int swz0 = ((l4 ^ (l15 & 7)) << 4);
  int swz1 = swz0 ^ 64;
  f32x4 acc[8][4];
  #pragma unroll
  for (int m = 0; m < 8; ++m)
    #pragma unroll
    for (int n = 0; n < 4; ++n) acc[m][n] = (f32x4){0.f, 0.f, 0.f, 0.f};
  int NT = K >> 6;
  stageB(0, 0, 0); stageB(0, 0, 1); stageA(0, 0);
  stageB(1, 1, 0); stageB(1, 1, 1); stageA(1, 1);
  WAIT_VM8();
  BARRIER();
  for (int kt = 0; kt < NT; ++kt) {
    int c = kt & 1;
    const char* base = ls + c * 65536;
    bool stg = (kt + 2) < NT;
    short8 bf[4][2], af[2][2];
    #pragma unroll
    for (int nf = 0; nf < 4; ++nf) {
      const char* p = base + bRdBase + (bRow0 + nf * 16 + l15) * 128;
      bf[nf][0] = *(const short8*)(p + swz0);
      bf[nf][1] = *(const short8*)(p + swz1);
    }
    LOAD_A(0);
    BARRIER();
    PH_MFMA(0);
    BARRIER();
    if (stg) stageB(c, kt + 2, 0);
    LOAD_A(1);
    BARRIER();
    PH_MFMA(1);
    BARRIER();
    if (stg) stageB(c, kt + 2, 1);
    LOAD_A(2);
    BARRIER();
    PH_MFMA(2);
    BARRIER();
    LOAD_A(3);
    WAIT_LGKM0();
    BARRIER();
    if (stg) stageA(c, kt + 2);
    PH_MFMA(3);
    if (stg) { WAIT_VM8(); } else { WAIT_VM0(); }
    BARRIER();
  }
  int b = (tm >> 7) + wm;
  #pragma unroll
  for (int nf = 0; nf < 4; ++nf) {
    int colg = tn + wn * 64 + nf * 16 + l15;
    float bv = bias[colg];
    float s = 0.f;
    #pragma unroll
    for (int mf = 0; mf < 8; ++mf)
      #pragma unroll
      for (int j = 0; j < 4; ++j) s += acc[mf][nf][j];
    s += 32.0f * bv;
    s += __shfl_xor(s, 16);
    s += __shfl_xor(s, 32);
    float cls = x[(size_t)b * 129 * 1024 + colg] + s * (1.0f / 128.0f);
    if (l4 == 0)
      Out[((size_t)b * 129) * 1024 + colg] = cls;
    #pragma unroll
    for (int mf = 0; mf < 8; ++mf) {
      #pragma unroll
      for (int j = 0; j < 4; ++j) {
        int tok = mf * 16 + l4 * 4 + j;
        Out[((size_t)b * 129 + 1 + tok) * 1024 + colg] = acc[mf][nf][j] + bv + cls;
      }
    }
  }
}

// ---------------- host ----------------
extern "C" void kernel_launch(void* const* d_in, const int* in_sizes, int n_in,
                              void* d_out, int out_size, void* d_ws, size_t ws_size,
                              hipStream_t stream) {
  const float* x        = (const float*)d_in[0];
  const float* w_q_ant  = (const float*)d_in[1];
  const float* b_q_ant  = (const float*)d_in[2];
  const float* w_k_ant  = (const float*)d_in[3];
  const float* b_k_ant  = (const float*)d_in[4];
  const float* w_v_ant  = (const float*)d_in[5];
  const float* b_v_ant  = (const float*)d_in[6];
  const float* w_q_freq = (const float*)d_in[7];
  const float* b_q_freq = (const float*)d_in[8];
  const float* w_k_freq = (const float*)d_in[9];
  const float* b_k_freq = (const float*)d_in[10];
  const float* w_v_freq = (const float*)d_in[11];
  const float* b_v_freq = (const float*)d_in[12];
  const float* w_out    = (const float*)d_in[13];
  const float* b_out    = (const float*)d_in[14];

  char* ws = (char*)d_ws;
  size_t off = 0;
  auto carve = [&](size_t bytes) {
    char* p = ws + off;
    off += (bytes + 255) & ~(size_t)255;
    return p;
  };
  short* wcat_ant  = (short*)carve((size_t)3072 * 1024 * 2);
  short* wcat_freq = (short*)carve((size_t)3072 * 1024 * 2);
  short* wout_bf   = (short*)carve((size_t)1024 * 1024 * 2);
  float* bcat_ant  = (float*)carve(3072 * 4);
  float* bcat_freq = (float*)carve(3072 * 4);
  short* bufA = (short*)carve((size_t)65536 * 1024 * 2);  // x_ant
  short* bufF = (short*)carve((size_t)65536 * 1024 * 2);  // x_freq
  short* bufG = (short*)carve((size_t)65536 * 1024 * 2);  // grid_flat
  (void)ws_size; (void)in_sizes; (void)n_in; (void)out_size;

  hipFuncSetAttribute((const void*)gemm_attn<1>,
                      hipFuncAttributeMaxDynamicSharedMemorySize, 131072);
  hipFuncSetAttribute((const void*)gemm_attn<2>,
                      hipFuncAttributeMaxDynamicSharedMemorySize, 131072);
  hipFuncSetAttribute((const void*)gemm_out,
                      hipFuncAttributeMaxDynamicSharedMemorySize, 131072);

  CvtW cw;
  cw.s[0] = w_q_ant;  cw.s[1] = w_k_ant;  cw.s[2] = w_v_ant;
  cw.s[3] = w_q_freq; cw.s[4] = w_k_freq; cw.s[5] = w_v_freq;
  cw.s[6] = w_out;
  cw.d[0] = wcat_ant;  cw.d[1] = wcat_ant;  cw.d[2] = wcat_ant;
  cw.d[3] = wcat_freq; cw.d[4] = wcat_freq; cw.d[5] = wcat_freq;
  cw.d[6] = wout_bf;
  cvt_weights<<<512, 256, 0, stream>>>(cw);

  CvtB cb;
  cb.s[0] = b_q_ant;  cb.s[1] = b_k_ant;  cb.s[2] = b_v_ant;
  cb.s[3] = b_q_freq; cb.s[4] = b_k_freq; cb.s[5] = b_v_freq;
  cb.d0 = bcat_ant; cb.d1 = bcat_freq;
  cvt_bias<<<6, 256, 0, stream>>>(cb);

  permute_x<<<32768, 256, 0, stream>>>(x, bufA);

  // stage 1: fused qkv GEMM + ant attention -> x_freq
  gemm_attn<1><<<4096, 512, 131072, stream>>>(bufA, wcat_ant, bcat_ant, bufF, 1024);
  // stage 2: fused qkv GEMM + freq attention -> grid_flat
  gemm_attn<2><<<4096, 512, 131072, stream>>>(bufF, wcat_freq, bcat_freq, bufG, 1024);
  // out projection fused with mean/cls/concat -> d_out
  gemm_out<<<1024, 512, 131072, stream>>>(bufG, wout_bf, b_out, x, (float*)d_out,
                                          65536, 1024, 1024);
}